// Round 4
// baseline (205.063 us; speedup 1.0000x reference)
//
#include <hip/hip_runtime.h>
#include <hip/hip_bf16.h>
#include <stdint.h>

typedef __bf16 bf16;
typedef __bf16 bf16x8 __attribute__((ext_vector_type(8)));
typedef __bf16 bf16x4v __attribute__((ext_vector_type(4)));
typedef float  f32x4  __attribute__((ext_vector_type(4)));
typedef float  f32x16 __attribute__((ext_vector_type(16)));
typedef unsigned int u32x4 __attribute__((ext_vector_type(4)));

#define NB    8
#define SEQ   2048
#define EMB   512
#define NHEAD 8
#define HD    64

static __device__ __forceinline__ f32x4 mfma16(bf16x8 a, bf16x8 b, f32x4 c) {
    return __builtin_amdgcn_mfma_f32_16x16x32_bf16(a, b, c, 0, 0, 0);
}
static __device__ __forceinline__ f32x16 mfma32(bf16x8 a, bf16x8 b, f32x16 c) {
    return __builtin_amdgcn_mfma_f32_32x32x16_bf16(a, b, c, 0, 0, 0);
}
static __device__ __forceinline__ float ex2(float x) {
    float r; asm("v_exp_f32 %0, %1" : "=v"(r) : "v"(x)); return r;
}
static __device__ __forceinline__ unsigned pkbf(float lo, float hi) {
    unsigned d; asm("v_cvt_pk_bf16_f32 %0, %1, %2" : "=v"(d) : "v"(lo), "v"(hi)); return d;
}
static __device__ __forceinline__ void gload_lds16(const void* g, void* l) {
    __builtin_amdgcn_global_load_lds(
        (const __attribute__((address_space(1))) unsigned int*)g,
        (__attribute__((address_space(3))) unsigned int*)l, 16, 0, 0);
}

// ---------------------------------------------------------------------------
// Weights: fp32 [k][n] -> bf16 transposed [n][k], 4 matrices
// ---------------------------------------------------------------------------
__global__ __launch_bounds__(256) void prep_weights(
    const float* __restrict__ Wv, const float* __restrict__ Wk,
    const float* __restrict__ Wq, const float* __restrict__ Wo,
    bf16* __restrict__ wt)
{
    int idx = blockIdx.x * 256 + threadIdx.x;
    int w   = idx >> 18;
    int rem = idx & 262143;
    int k   = rem >> 9;
    int n   = rem & 511;
    const float* src = (w == 0) ? Wv : (w == 1) ? Wk : (w == 2) ? Wq : Wo;
    wt[(size_t)w * 262144 + (size_t)n * 512 + k] = (bf16)src[k * 512 + n];
}

// ---------------------------------------------------------------------------
// GEMM: C[16384][512] = A[16384][512] * W, B given transposed bf16 (unchanged)
// ---------------------------------------------------------------------------
template <bool A_F32, bool FINAL>
__global__ __launch_bounds__(256) void gemm_kernel(
    const void* __restrict__ Ap, const bf16* __restrict__ Bt,
    void* __restrict__ Cp, const float* __restrict__ bias)
{
    __shared__ __align__(16) bf16 As[128][72];
    __shared__ __align__(16) bf16 Bs[128][72];

    const int t    = threadIdx.x;
    const int lane = t & 63;
    const int wave = t >> 6;
    const int wr   = wave >> 1, wc = wave & 1;
    const int l15  = lane & 15, lg = lane >> 4;
    const long row0 = (long)blockIdx.x * 128;
    const int  col0 = blockIdx.y * 128;

    f32x4 acc[4][4];
#pragma unroll
    for (int i = 0; i < 4; i++)
#pragma unroll
        for (int j = 0; j < 4; j++) acc[i][j] = (f32x4){0.f, 0.f, 0.f, 0.f};

    for (int k0 = 0; k0 < 512; k0 += 64) {
        __syncthreads();
        if (A_F32) {
            const float* A = (const float*)Ap;
#pragma unroll
            for (int i = 0; i < 8; i++) {
                int c  = t + 256 * i;
                int r  = c >> 4;
                int cc = (c & 15) * 4;
                f32x4 v = *(const f32x4*)(A + (row0 + r) * 512 + k0 + cc);
                bf16x4v pk = { (bf16)v[0], (bf16)v[1], (bf16)v[2], (bf16)v[3] };
                *(bf16x4v*)&As[r][cc] = pk;
            }
        } else {
            const bf16* A = (const bf16*)Ap;
#pragma unroll
            for (int i = 0; i < 4; i++) {
                int c  = t + 256 * i;
                int r  = c >> 3;
                int cc = (c & 7) * 8;
                *(bf16x8*)&As[r][cc] = *(const bf16x8*)(A + (row0 + r) * 512 + k0 + cc);
            }
        }
#pragma unroll
        for (int i = 0; i < 4; i++) {
            int c  = t + 256 * i;
            int r  = c >> 3;
            int cc = (c & 7) * 8;
            *(bf16x8*)&Bs[r][cc] = *(const bf16x8*)(Bt + (size_t)(col0 + r) * 512 + k0 + cc);
        }
        __syncthreads();
#pragma unroll
        for (int kc = 0; kc < 64; kc += 32) {
            bf16x8 af[4], bfv[4];
#pragma unroll
            for (int mb = 0; mb < 4; mb++)
                af[mb] = *(bf16x8*)&As[wr * 64 + mb * 16 + l15][kc + lg * 8];
#pragma unroll
            for (int nb = 0; nb < 4; nb++)
                bfv[nb] = *(bf16x8*)&Bs[wc * 64 + nb * 16 + l15][kc + lg * 8];
#pragma unroll
            for (int mb = 0; mb < 4; mb++)
#pragma unroll
                for (int nb = 0; nb < 4; nb++)
                    acc[mb][nb] = mfma16(af[mb], bfv[nb], acc[mb][nb]);
        }
    }

#pragma unroll
    for (int mb = 0; mb < 4; mb++)
#pragma unroll
        for (int nb = 0; nb < 4; nb++)
#pragma unroll
            for (int r = 0; r < 4; r++) {
                long grow = row0 + wr * 64 + mb * 16 + lg * 4 + r;
                int  gcol = col0 + wc * 64 + nb * 16 + l15;
                float v = acc[mb][nb][r];
                if (FINAL) {
                    ((float*)Cp)[grow * 512 + gcol] = v + bias[gcol];
                } else {
                    ((bf16*)Cp)[grow * 512 + gcol] = (bf16)v;
                }
            }
}

// ---------------------------------------------------------------------------
// Flash attention, swapped-QK^T 32x32x16 structure.
// R4: 32 q-rows/wave (1 q-block), qt grid 4->8 => 512 blocks = 2 blocks/CU
// = 16 waves/CU (occupancy 2x vs R3). Otherwise identical to R3.
// ---------------------------------------------------------------------------
__global__ __launch_bounds__(512, 4) void attn_kernel(
    const bf16* __restrict__ Qg, const bf16* __restrict__ Kg,
    const bf16* __restrict__ Vg, const int* __restrict__ mask,
    bf16* __restrict__ ctx)
{
    __shared__ __align__(16) bf16 Ks[2][4096];   // [64 key][64 d], swizzled
    __shared__ __align__(16) bf16 Vt[2][4096];   // [64 d][64 key], swizzled
    __shared__ __align__(16) bf16 Ob[8][32 * 72];

    const int t    = threadIdx.x;
    const int lane = t & 63;
    const int w    = t >> 6;
    const int l31  = lane & 31;
    const int hi   = lane >> 5;
    const int qt = blockIdx.x, h = blockIdx.y, n = blockIdx.z;

    const size_t nbase   = (size_t)n * SEQ;
    const size_t headoff = (size_t)h * 64;
    const int q0 = qt * 256 + w * 32;

    // Q fragments: B-operand, col=q=l31, k-dim d = ds*16 + hi*8 + j
    bf16x8 qf[4];
#pragma unroll
    for (int ds = 0; ds < 4; ++ds)
        qf[ds] = *(const bf16x8*)(Qg + (nbase + q0 + l31) * 512 + headoff + ds * 16 + hi * 8);

    f32x16 o[2] = {};             // [db], O^T: row=d-local, col=q
    float m_run = -1e30f;
    float l_run = 0.f;

    // staging source pointers
    const bf16* kg = Kg + (nbase + w * 8 + (lane >> 3)) * 512 + headoff + (((lane & 7) ^ (lane >> 3)) << 3);
    const bf16* vg = Vg + (nbase + lane) * 512 + headoff + w * 8;
    const int*  mp = mask + n * SEQ;

    // prologue: stage tile 0
    gload_lds16(kg, (char*)&Ks[0][0] + w * 1024);
    {
        bf16x8 v0 = *(const bf16x8*)vg;
        char* vb = (char*)&Vt[0][0];
#pragma unroll
        for (int j = 0; j < 8; ++j)
            *(bf16*)(vb + (8 * w + j) * 128 + ((2 * lane) ^ (j << 4))) = v0[j];
    }
    __syncthreads();

    const float SC = 0.18033688011f;   // 0.125 * log2(e)

    int cur = 0;
    for (int kt = 0; kt < 32; ++kt) {
        // async prefetch of next tile (T14): issue now, consume at loop end
        bf16x8 vstage;
        if (kt < 31) {
            gload_lds16(kg + (size_t)(kt + 1) * 64 * 512, (char*)&Ks[cur ^ 1][0] + w * 1024);
            vstage = *(const bf16x8*)(vg + (size_t)(kt + 1) * 64 * 512);
        }
        int mv = mp[kt * 64 + lane];

        // ---- QK^T swapped: p[kb], C row = key-local, col = q ----
        f32x16 p[2] = {};
        const char* kb_base = (const char*)&Ks[cur][0];
#pragma unroll
        for (int ds = 0; ds < 4; ++ds) {
            int sw = (ds * 32 + hi * 16) ^ ((l31 & 7) << 4);
            bf16x8 kf0 = *(const bf16x8*)(kb_base + (l31) * 128 + sw);
            bf16x8 kf1 = *(const bf16x8*)(kb_base + (32 + l31) * 128 + sw);
            p[0] = mfma32(kf0, qf[ds], p[0]);
            p[1] = mfma32(kf1, qf[ds], p[1]);
        }

        // ---- mask (rare path; bench mask is all-ones) ----
        unsigned long long mb = __ballot(mv != 0);
        if (mb != ~0ULL) {
#pragma unroll
            for (int kb = 0; kb < 2; ++kb) {
                float* pp = (float*)&p[kb];
#pragma unroll
                for (int r = 0; r < 16; ++r) {
                    int kk = kb * 32 + (r & 3) + 8 * (r >> 2) + 4 * hi;
                    if (!((mb >> kk) & 1)) pp[r] = -1e30f;
                }
            }
        }

        // ---- in-register online softmax (base-2) + pack ----
        u32x4 bq[4];
        {
            float* p0 = (float*)&p[0];
            float* p1 = (float*)&p[1];
            float tm = fmaxf(p0[0], p1[0]);
#pragma unroll
            for (int r = 1; r < 16; ++r) tm = fmaxf(tm, fmaxf(p0[r], p1[r]));
            float tms = tm * SC;
            float rmax = fmaxf(tms, __shfl_xor(tms, 32));
            if (!__all(rmax <= m_run + 8.0f)) {   // defer-max (T13)
                float mn  = fmaxf(m_run, rmax);
                float fac = ex2(m_run - mn);
#pragma unroll
                for (int db = 0; db < 2; ++db) {
                    float* oo = (float*)&o[db];
#pragma unroll
                    for (int r = 0; r < 16; ++r) oo[r] *= fac;
                }
                l_run *= fac;
                m_run = mn;
            }
            float negm = -m_run;
            float sl = 0.f;
#pragma unroll
            for (int r = 0; r < 16; ++r) { float e = ex2(fmaf(p0[r], SC, negm)); p0[r] = e; sl += e; }
#pragma unroll
            for (int r = 0; r < 16; ++r) { float e = ex2(fmaf(p1[r], SC, negm)); p1[r] = e; sl += e; }
            l_run += sl + __shfl_xor(sl, 32);

            // P -> bf16 B-fragments. Needed: j-th elem = P[key=ks*16+hi*8+j][q=l31].
            // Own regs give keys {0-3,8-11}+4*hi; partner (lane^32) has the rest.
#pragma unroll
            for (int ks = 0; ks < 4; ++ks) {
                float* ps = (ks >> 1) ? p1 : p0;
                int bo = (ks & 1) * 8;
                unsigned A  = pkbf(ps[bo + 0], ps[bo + 1]);   // keys base+{0,1}+4hi
                unsigned B  = pkbf(ps[bo + 2], ps[bo + 3]);   // keys base+{2,3}+4hi
                unsigned C  = pkbf(ps[bo + 4], ps[bo + 5]);   // keys base+{8,9}+4hi
                unsigned Dw = pkbf(ps[bo + 6], ps[bo + 7]);   // keys base+{10,11}+4hi
                unsigned xA = __shfl_xor(A, 32);
                unsigned xB = __shfl_xor(B, 32);
                unsigned xC = __shfl_xor(C, 32);
                unsigned xD = __shfl_xor(Dw, 32);
                unsigned w0 = hi ? xC : A;    // j0,j1: keys base + hi*8 + {0,1}
                unsigned w1 = hi ? xD : B;    // j2,j3
                unsigned w2 = hi ? C : xA;    // j4,j5
                unsigned w3 = hi ? Dw : xB;   // j6,j7
                bq[ks] = (u32x4){w0, w1, w2, w3};
            }
        }

        // ---- PV: o[db] += V^T slab (A) x P^T (B) ----
        const char* vb_base = (const char*)&Vt[cur][0];
#pragma unroll
        for (int ks = 0; ks < 4; ++ks) {
            int sw = (ks * 32 + hi * 16) ^ ((l31 & 7) << 4);
            bf16x8 vf0 = *(const bf16x8*)(vb_base + (l31) * 128 + sw);
            bf16x8 vf1 = *(const bf16x8*)(vb_base + (32 + l31) * 128 + sw);
            union { u32x4 u; bf16x8 v; } c0;
            c0.u = bq[ks];
            o[0] = mfma32(vf0, c0.v, o[0]);
            o[1] = mfma32(vf1, c0.v, o[1]);
        }

        // ---- write prefetched V (vmcnt wait inserted by compiler) ----
        if (kt < 31) {
            char* vb = (char*)&Vt[cur ^ 1][0];
#pragma unroll
            for (int j = 0; j < 8; ++j)
                *(bf16*)(vb + (8 * w + j) * 128 + ((2 * lane) ^ (j << 4))) = vstage[j];
        }
        __syncthreads();
        cur ^= 1;
    }

    // ---- epilogue: O^T -> LDS transpose -> coalesced bf16 store ----
    {
        float inv = 1.f / l_run;
        bf16* ob = &Ob[w][0];
#pragma unroll
        for (int db = 0; db < 2; ++db) {
            float* oo = (float*)&o[db];
#pragma unroll
            for (int r = 0; r < 16; ++r) {
                int d = db * 32 + (r & 3) + 8 * (r >> 2) + 4 * hi;
                ob[l31 * 72 + d] = (bf16)(oo[r] * inv);
            }
        }
#pragma unroll
        for (int i = 0; i < 2; ++i)
#pragma unroll
            for (int half = 0; half < 2; ++half) {
                int ql = i * 16 + (lane >> 2);
                int d8 = (lane & 3) * 8 + half * 32;
                bf16x8 vv = *(const bf16x8*)(ob + ql * 72 + d8);
                *(bf16x8*)(ctx + (nbase + q0 + ql) * 512 + headoff + d8) = vv;
            }
    }
}

// ---------------------------------------------------------------------------
extern "C" void kernel_launch(void* const* d_in, const int* in_sizes, int n_in,
                              void* d_out, int out_size, void* d_ws, size_t ws_size,
                              hipStream_t stream) {
    (void)in_sizes; (void)n_in; (void)out_size; (void)ws_size;
    const float* values = (const float*)d_in[0];
    const float* keys   = (const float*)d_in[1];
    const float* query  = (const float*)d_in[2];
    const int*   mask   = (const int*)d_in[3];
    const float* Wv = (const float*)d_in[4];
    const float* Wk = (const float*)d_in[5];
    const float* Wq = (const float*)d_in[6];
    const float* Wo = (const float*)d_in[7];
    const float* bo = (const float*)d_in[8];
    float* out = (float*)d_out;

    char* ws = (char*)d_ws;
    bf16* wt = (bf16*)(ws);                       //  2 MB: 4 x [512][512]
    bf16* Qb = (bf16*)(ws + ((size_t)2  << 20));  // 16 MB
    bf16* Kb = (bf16*)(ws + ((size_t)18 << 20));  // 16 MB
    bf16* Vb = (bf16*)(ws + ((size_t)34 << 20));  // 16 MB
    bf16* Cb = (bf16*)(ws + ((size_t)50 << 20));  // 16 MB

    prep_weights<<<4096, 256, 0, stream>>>(Wv, Wk, Wq, Wo, wt);
    gemm_kernel<true, false><<<dim3(128, 4), 256, 0, stream>>>(values, wt,              Vb, nullptr);
    gemm_kernel<true, false><<<dim3(128, 4), 256, 0, stream>>>(keys,   wt + 262144,     Kb, nullptr);
    gemm_kernel<true, false><<<dim3(128, 4), 256, 0, stream>>>(query,  wt + 2 * 262144, Qb, nullptr);
    attn_kernel<<<dim3(8, 8, 8), 512, 0, stream>>>(Qb, Kb, Vb, mask, Cb);
    gemm_kernel<false, true><<<dim3(128, 4), 256, 0, stream>>>(Cb, wt + 3 * 262144, out, bo);
}

// Round 5
// 179.805 us; speedup vs baseline: 1.1405x; 1.1405x over previous
//
#include <hip/hip_runtime.h>
#include <hip/hip_bf16.h>
#include <stdint.h>

typedef __bf16 bf16;
typedef __bf16 bf16x8 __attribute__((ext_vector_type(8)));
typedef __bf16 bf16x4v __attribute__((ext_vector_type(4)));
typedef float  f32x4  __attribute__((ext_vector_type(4)));
typedef float  f32x16 __attribute__((ext_vector_type(16)));
typedef unsigned int u32x4 __attribute__((ext_vector_type(4)));

#define NB    8
#define SEQ   2048
#define EMB   512
#define NHEAD 8
#define HD    64

static __device__ __forceinline__ f32x4 mfma16(bf16x8 a, bf16x8 b, f32x4 c) {
    return __builtin_amdgcn_mfma_f32_16x16x32_bf16(a, b, c, 0, 0, 0);
}
static __device__ __forceinline__ f32x16 mfma32(bf16x8 a, bf16x8 b, f32x16 c) {
    return __builtin_amdgcn_mfma_f32_32x32x16_bf16(a, b, c, 0, 0, 0);
}
static __device__ __forceinline__ float ex2(float x) {
    float r; asm("v_exp_f32 %0, %1" : "=v"(r) : "v"(x)); return r;
}
static __device__ __forceinline__ unsigned pkbf(float lo, float hi) {
    unsigned d; asm("v_cvt_pk_bf16_f32 %0, %1, %2" : "=v"(d) : "v"(lo), "v"(hi)); return d;
}
static __device__ __forceinline__ float max3(float a, float b, float c) {
    return fmaxf(fmaxf(a, b), c);   // fuses to v_max3_f32
}
static __device__ __forceinline__ void gload_lds16(const void* g, void* l) {
    __builtin_amdgcn_global_load_lds(
        (const __attribute__((address_space(1))) unsigned int*)g,
        (__attribute__((address_space(3))) unsigned int*)l, 16, 0, 0);
}
#define PRIO1 __builtin_amdgcn_s_setprio(1)
#define PRIO0 __builtin_amdgcn_s_setprio(0)

// ---------------------------------------------------------------------------
// Weights: fp32 [k][n] -> bf16 transposed [n][k], 4 matrices
// ---------------------------------------------------------------------------
__global__ __launch_bounds__(256) void prep_weights(
    const float* __restrict__ Wv, const float* __restrict__ Wk,
    const float* __restrict__ Wq, const float* __restrict__ Wo,
    bf16* __restrict__ wt)
{
    int idx = blockIdx.x * 256 + threadIdx.x;
    int w   = idx >> 18;
    int rem = idx & 262143;
    int k   = rem >> 9;
    int n   = rem & 511;
    const float* src = (w == 0) ? Wv : (w == 1) ? Wk : (w == 2) ? Wq : Wo;
    wt[(size_t)w * 262144 + (size_t)n * 512 + k] = (bf16)src[k * 512 + n];
}

// ---------------------------------------------------------------------------
// GEMM: C[16384][512] = A[16384][512] * W, B given transposed bf16 (unchanged)
// ---------------------------------------------------------------------------
template <bool A_F32, bool FINAL>
__global__ __launch_bounds__(256) void gemm_kernel(
    const void* __restrict__ Ap, const bf16* __restrict__ Bt,
    void* __restrict__ Cp, const float* __restrict__ bias)
{
    __shared__ __align__(16) bf16 As[128][72];
    __shared__ __align__(16) bf16 Bs[128][72];

    const int t    = threadIdx.x;
    const int lane = t & 63;
    const int wave = t >> 6;
    const int wr   = wave >> 1, wc = wave & 1;
    const int l15  = lane & 15, lg = lane >> 4;
    const long row0 = (long)blockIdx.x * 128;
    const int  col0 = blockIdx.y * 128;

    f32x4 acc[4][4];
#pragma unroll
    for (int i = 0; i < 4; i++)
#pragma unroll
        for (int j = 0; j < 4; j++) acc[i][j] = (f32x4){0.f, 0.f, 0.f, 0.f};

    for (int k0 = 0; k0 < 512; k0 += 64) {
        __syncthreads();
        if (A_F32) {
            const float* A = (const float*)Ap;
#pragma unroll
            for (int i = 0; i < 8; i++) {
                int c  = t + 256 * i;
                int r  = c >> 4;
                int cc = (c & 15) * 4;
                f32x4 v = *(const f32x4*)(A + (row0 + r) * 512 + k0 + cc);
                bf16x4v pk = { (bf16)v[0], (bf16)v[1], (bf16)v[2], (bf16)v[3] };
                *(bf16x4v*)&As[r][cc] = pk;
            }
        } else {
            const bf16* A = (const bf16*)Ap;
#pragma unroll
            for (int i = 0; i < 4; i++) {
                int c  = t + 256 * i;
                int r  = c >> 3;
                int cc = (c & 7) * 8;
                *(bf16x8*)&As[r][cc] = *(const bf16x8*)(A + (row0 + r) * 512 + k0 + cc);
            }
        }
#pragma unroll
        for (int i = 0; i < 4; i++) {
            int c  = t + 256 * i;
            int r  = c >> 3;
            int cc = (c & 7) * 8;
            *(bf16x8*)&Bs[r][cc] = *(const bf16x8*)(Bt + (size_t)(col0 + r) * 512 + k0 + cc);
        }
        __syncthreads();
#pragma unroll
        for (int kc = 0; kc < 64; kc += 32) {
            bf16x8 af[4], bfv[4];
#pragma unroll
            for (int mb = 0; mb < 4; mb++)
                af[mb] = *(bf16x8*)&As[wr * 64 + mb * 16 + l15][kc + lg * 8];
#pragma unroll
            for (int nb = 0; nb < 4; nb++)
                bfv[nb] = *(bf16x8*)&Bs[wc * 64 + nb * 16 + l15][kc + lg * 8];
#pragma unroll
            for (int mb = 0; mb < 4; mb++)
#pragma unroll
                for (int nb = 0; nb < 4; nb++)
                    acc[mb][nb] = mfma16(af[mb], bfv[nb], acc[mb][nb]);
        }
    }

#pragma unroll
    for (int mb = 0; mb < 4; mb++)
#pragma unroll
        for (int nb = 0; nb < 4; nb++)
#pragma unroll
            for (int r = 0; r < 4; r++) {
                long grow = row0 + wr * 64 + mb * 16 + lg * 4 + r;
                int  gcol = col0 + wc * 64 + nb * 16 + l15;
                float v = acc[mb][nb][r];
                if (FINAL) {
                    ((float*)Cp)[grow * 512 + gcol] = v + bias[gcol];
                } else {
                    ((bf16*)Cp)[grow * 512 + gcol] = (bf16)v;
                }
            }
}

// ---------------------------------------------------------------------------
// Flash attention, swapped-QK^T 32x32x16. R5: 2 tiles per barrier epoch
// (4 LDS buffers), T15-lite reorder (QK(B)+PV(A) MFMA burst covers sm(B)),
// setprio around MFMA, max3 tree + 4-acc sums, hoisted mask flag.
// 512 thr = 8 waves, 64 q/wave, grid 4x8x8 (R3 geometry).
// ---------------------------------------------------------------------------
__global__ __launch_bounds__(512, 2) void attn_kernel(
    const bf16* __restrict__ Qg, const bf16* __restrict__ Kg,
    const bf16* __restrict__ Vg, const int* __restrict__ mask,
    bf16* __restrict__ ctx)
{
    __shared__ __align__(16) bf16 Ks[4][4096];   // [64 key][64 d], swizzled
    __shared__ __align__(16) bf16 Vt[4][4096];   // [64 d][64 key], swizzled
    __shared__ __align__(16) bf16 Ob[8][32 * 72];

    const int t    = threadIdx.x;
    const int lane = t & 63;
    const int w    = t >> 6;
    const int l31  = lane & 31;
    const int hi   = lane >> 5;
    const int qt = blockIdx.x, h = blockIdx.y, n = blockIdx.z;

    const size_t nbase   = (size_t)n * SEQ;
    const size_t headoff = (size_t)h * 64;
    const int q0 = qt * 512 + w * 64;

    // block-wide "mask all ones" flag (512 thr x 4 = 2048 entries)
    int* mflags = (int*)&Ob[0][0];
    {
        const int* mp0 = mask + n * SEQ + t * 4;
        int mok = (mp0[0] != 0) & (mp0[1] != 0) & (mp0[2] != 0) & (mp0[3] != 0);
        unsigned long long b = __ballot(mok);
        if (lane == 0) mflags[w] = (b == ~0ULL) ? 1 : 0;
    }

    // Q fragments: B-operand, col=q=l31, k-dim d = ds*16 + hi*8 + j
    bf16x8 qf[2][4];
#pragma unroll
    for (int qb = 0; qb < 2; ++qb)
#pragma unroll
        for (int ds = 0; ds < 4; ++ds)
            qf[qb][ds] = *(const bf16x8*)(Qg + (nbase + q0 + qb * 32 + l31) * 512 + headoff + ds * 16 + hi * 8);

    f32x16 o[2][2] = {};          // [db][qb], O^T: row=d-local, col=q
    float m_run[2] = {-1e30f, -1e30f};
    float l_run[2] = {0.f, 0.f};

    const bf16* kg = Kg + (nbase + w * 8 + (lane >> 3)) * 512 + headoff + (((lane & 7) ^ (lane >> 3)) << 3);
    const bf16* vg = Vg + (nbase + lane) * 512 + headoff + w * 8;
    const int*  mp = mask + n * SEQ;

#define VSCAT(VR, VB) do {                                                    \
        char* vbp = (char*)(VB);                                              \
        _Pragma("unroll") for (int j = 0; j < 8; ++j)                         \
            *(bf16*)(vbp + (8 * w + j) * 128 + ((2 * lane) ^ (j << 4))) = (VR)[j]; \
    } while (0)

    // prologue: stage tiles 0,1
    gload_lds16(kg,                     (char*)&Ks[0][0] + w * 1024);
    gload_lds16(kg + (size_t)64 * 512,  (char*)&Ks[1][0] + w * 1024);
    bf16x8 vrA = *(const bf16x8*)vg;
    bf16x8 vrB = *(const bf16x8*)(vg + (size_t)64 * 512);
    VSCAT(vrA, &Vt[0][0]);
    VSCAT(vrB, &Vt[1][0]);
    __syncthreads();
    const int maskall = mflags[0] & mflags[1] & mflags[2] & mflags[3] &
                        mflags[4] & mflags[5] & mflags[6] & mflags[7];

    const float SC = 0.18033688011f;   // 0.125 * log2(e)

    f32x16 p[2][2];
    u32x4  bq[2][4];

#define QK_TILE(KB) do {                                                      \
        const char* kbb = (const char*)(KB);                                  \
        f32x16 zz = {};                                                       \
        p[0][0] = zz; p[0][1] = zz; p[1][0] = zz; p[1][1] = zz;               \
        PRIO1;                                                                \
        _Pragma("unroll")                                                     \
        for (int ds = 0; ds < 4; ++ds) {                                      \
            int sw = (ds * 32 + hi * 16) ^ ((l31 & 7) << 4);                  \
            bf16x8 kf0 = *(const bf16x8*)(kbb + l31 * 128 + sw);              \
            bf16x8 kf1 = *(const bf16x8*)(kbb + (32 + l31) * 128 + sw);       \
            p[0][0] = mfma32(kf0, qf[0][ds], p[0][0]);                        \
            p[1][0] = mfma32(kf0, qf[1][ds], p[1][0]);                        \
            p[0][1] = mfma32(kf1, qf[0][ds], p[0][1]);                        \
            p[1][1] = mfma32(kf1, qf[1][ds], p[1][1]);                        \
        }                                                                     \
        PRIO0;                                                                \
    } while (0)

#define MASK_TILE(T) do {                                                     \
        if (!maskall) {                                                       \
            int mv = mp[(T) * 64 + lane];                                     \
            unsigned long long mb = __ballot(mv != 0);                        \
            if (mb != ~0ULL) {                                                \
                _Pragma("unroll") for (int qb = 0; qb < 2; ++qb)              \
                _Pragma("unroll") for (int kb = 0; kb < 2; ++kb) {            \
                    float* pp = (float*)&p[qb][kb];                           \
                    _Pragma("unroll") for (int r = 0; r < 16; ++r) {          \
                        int kk = kb * 32 + (r & 3) + 8 * (r >> 2) + 4 * hi;   \
                        if (!((mb >> kk) & 1)) pp[r] = -1e30f;                \
                    }                                                         \
                }                                                             \
            }                                                                 \
        }                                                                     \
    } while (0)

#define SM_PACK do {                                                          \
        _Pragma("unroll")                                                     \
        for (int qb = 0; qb < 2; ++qb) {                                      \
            float* p0 = (float*)&p[qb][0];                                    \
            float* p1 = (float*)&p[qb][1];                                    \
            float g0 = max3(p0[0], p0[1], p0[2]);                             \
            float g1 = max3(p0[3], p0[4], p0[5]);                             \
            float g2 = max3(p0[6], p0[7], p0[8]);                             \
            float g3 = max3(p0[9], p0[10], p0[11]);                           \
            float g4 = max3(p0[12], p0[13], p0[14]);                          \
            float g5 = max3(p0[15], p1[0], p1[1]);                            \
            float g6 = max3(p1[2], p1[3], p1[4]);                             \
            float g7 = max3(p1[5], p1[6], p1[7]);                             \
            float g8 = max3(p1[8], p1[9], p1[10]);                            \
            float g9 = max3(p1[11], p1[12], p1[13]);                          \
            float g10 = fmaxf(p1[14], p1[15]);                                \
            float t0 = max3(g0, g1, g2), t1 = max3(g3, g4, g5);               \
            float t2 = max3(g6, g7, g8), t3 = max3(g9, g10, t0);              \
            float tm = max3(t1, t2, t3);                                      \
            float tms = tm * SC;                                              \
            float rmax = fmaxf(tms, __shfl_xor(tms, 32));                     \
            if (!__all(rmax <= m_run[qb] + 8.0f)) {                           \
                float mn  = fmaxf(m_run[qb], rmax);                           \
                float fac = ex2(m_run[qb] - mn);                              \
                _Pragma("unroll") for (int db = 0; db < 2; ++db) {            \
                    float* oo = (float*)&o[db][qb];                           \
                    _Pragma("unroll") for (int r = 0; r < 16; ++r) oo[r] *= fac; \
                }                                                             \
                l_run[qb] *= fac; m_run[qb] = mn;                             \
            }                                                                 \
            float negm = -m_run[qb];                                          \
            float sa0 = 0.f, sa1 = 0.f, sa2 = 0.f, sa3 = 0.f;                 \
            _Pragma("unroll") for (int r = 0; r < 16; r += 4) {               \
                float e0 = ex2(fmaf(p0[r],   SC, negm)); p0[r]   = e0; sa0 += e0; \
                float e1 = ex2(fmaf(p0[r+1], SC, negm)); p0[r+1] = e1; sa1 += e1; \
                float e2 = ex2(fmaf(p0[r+2], SC, negm)); p0[r+2] = e2; sa2 += e2; \
                float e3 = ex2(fmaf(p0[r+3], SC, negm)); p0[r+3] = e3; sa3 += e3; \
            }                                                                 \
            _Pragma("unroll") for (int r = 0; r < 16; r += 4) {               \
                float e0 = ex2(fmaf(p1[r],   SC, negm)); p1[r]   = e0; sa0 += e0; \
                float e1 = ex2(fmaf(p1[r+1], SC, negm)); p1[r+1] = e1; sa1 += e1; \
                float e2 = ex2(fmaf(p1[r+2], SC, negm)); p1[r+2] = e2; sa2 += e2; \
                float e3 = ex2(fmaf(p1[r+3], SC, negm)); p1[r+3] = e3; sa3 += e3; \
            }                                                                 \
            float sl = (sa0 + sa1) + (sa2 + sa3);                             \
            l_run[qb] += sl + __shfl_xor(sl, 32);                             \
            _Pragma("unroll")                                                 \
            for (int ks = 0; ks < 4; ++ks) {                                  \
                float* ps = (ks >> 1) ? p1 : p0;                              \
                int bo = (ks & 1) * 8;                                        \
                unsigned A  = pkbf(ps[bo + 0], ps[bo + 1]);                   \
                unsigned B  = pkbf(ps[bo + 2], ps[bo + 3]);                   \
                unsigned C  = pkbf(ps[bo + 4], ps[bo + 5]);                   \
                unsigned Dw = pkbf(ps[bo + 6], ps[bo + 7]);                   \
                unsigned xA = __shfl_xor(A, 32), xB = __shfl_xor(B, 32);      \
                unsigned xC = __shfl_xor(C, 32), xD = __shfl_xor(Dw, 32);     \
                unsigned w0 = hi ? xC : A, w1 = hi ? xD : B;                  \
                unsigned w2 = hi ? C : xA, w3 = hi ? Dw : xB;                 \
                bq[qb][ks] = (u32x4){w0, w1, w2, w3};                         \
            }                                                                 \
        }                                                                     \
    } while (0)

#define PV_TILE(VB) do {                                                      \
        const char* vbb = (const char*)(VB);                                  \
        PRIO1;                                                                \
        _Pragma("unroll")                                                     \
        for (int ks = 0; ks < 4; ++ks) {                                      \
            int sw = (ks * 32 + hi * 16) ^ ((l31 & 7) << 4);                  \
            bf16x8 vf0 = *(const bf16x8*)(vbb + l31 * 128 + sw);              \
            bf16x8 vf1 = *(const bf16x8*)(vbb + (32 + l31) * 128 + sw);       \
            union { u32x4 u; bf16x8 v; } c0, c1;                              \
            c0.u = bq[0][ks]; c1.u = bq[1][ks];                               \
            o[0][0] = mfma32(vf0, c0.v, o[0][0]);                             \
            o[0][1] = mfma32(vf0, c1.v, o[0][1]);                             \
            o[1][0] = mfma32(vf1, c0.v, o[1][0]);                             \
            o[1][1] = mfma32(vf1, c1.v, o[1][1]);                             \
        }                                                                     \
        PRIO0;                                                                \
    } while (0)

    u32x4 bqA[2][4];

    for (int e = 0; e < 16; ++e) {
        const int bA = (e & 1) * 2, bB = bA + 1;
        const int nA = bA ^ 2,      nB = bB ^ 2;
        // T14: issue next-epoch staging early
        if (e < 15) {
            gload_lds16(kg + (size_t)(2 * e + 2) * 64 * 512, (char*)&Ks[nA][0] + w * 1024);
            gload_lds16(kg + (size_t)(2 * e + 3) * 64 * 512, (char*)&Ks[nB][0] + w * 1024);
            vrA = *(const bf16x8*)(vg + (size_t)(2 * e + 2) * 64 * 512);
            vrB = *(const bf16x8*)(vg + (size_t)(2 * e + 3) * 64 * 512);
        }
        // tile A = 2e
        QK_TILE(&Ks[bA][0]);
        MASK_TILE(2 * e);
        SM_PACK;
#pragma unroll
        for (int qb = 0; qb < 2; ++qb)
#pragma unroll
            for (int ks = 0; ks < 4; ++ks) bqA[qb][ks] = bq[qb][ks];
        // tile B = 2e+1: QK(B) + PV(A) MFMA burst covers sm(B)'s inputs
        QK_TILE(&Ks[bB][0]);
        PV_TILE(&Vt[bA][0]);   // consumes bqA
#pragma unroll
        for (int qb = 0; qb < 2; ++qb)
#pragma unroll
            for (int ks = 0; ks < 4; ++ks) bq[qb][ks] = bqA[qb][ks];   // dead; keeps names tidy
        MASK_TILE(2 * e + 1);
        SM_PACK;
        PV_TILE(&Vt[bB][0]);
        // late scatters for next epoch
        if (e < 15) {
            VSCAT(vrA, &Vt[nA][0]);
            VSCAT(vrB, &Vt[nB][0]);
        }
        __syncthreads();
    }

    // ---- epilogue: O^T -> LDS transpose -> coalesced bf16 store ----
#pragma unroll
    for (int qb = 0; qb < 2; ++qb) {
        float inv = 1.f / l_run[qb];
        bf16* ob = &Ob[w][0];
#pragma unroll
        for (int db = 0; db < 2; ++db) {
            float* oo = (float*)&o[db][qb];
#pragma unroll
            for (int r = 0; r < 16; ++r) {
                int d = db * 32 + (r & 3) + 8 * (r >> 2) + 4 * hi;
                ob[l31 * 72 + d] = (bf16)(oo[r] * inv);
            }
        }
#pragma unroll
        for (int i = 0; i < 2; ++i)
#pragma unroll
            for (int half = 0; half < 2; ++half) {
                int ql = i * 16 + (lane >> 2);
                int d8 = (lane & 3) * 8 + half * 32;
                bf16x8 vv = *(const bf16x8*)(ob + ql * 72 + d8);
                *(bf16x8*)(ctx + (nbase + q0 + qb * 32 + ql) * 512 + headoff + d8) = vv;
            }
    }
#undef VSCAT
#undef QK_TILE
#undef MASK_TILE
#undef SM_PACK
#undef PV_TILE
}

// ---------------------------------------------------------------------------
extern "C" void kernel_launch(void* const* d_in, const int* in_sizes, int n_in,
                              void* d_out, int out_size, void* d_ws, size_t ws_size,
                              hipStream_t stream) {
    (void)in_sizes; (void)n_in; (void)out_size; (void)ws_size;
    const float* values = (const float*)d_in[0];
    const float* keys   = (const float*)d_in[1];
    const float* query  = (const float*)d_in[2];
    const int*   mask   = (const int*)d_in[3];
    const float* Wv = (const float*)d_in[4];
    const float* Wk = (const float*)d_in[5];
    const float* Wq = (const float*)d_in[6];
    const float* Wo = (const float*)d_in[7];
    const float* bo = (const float*)d_in[8];
    float* out = (float*)d_out;

    char* ws = (char*)d_ws;
    bf16* wt = (bf16*)(ws);                       //  2 MB: 4 x [512][512]
    bf16* Qb = (bf16*)(ws + ((size_t)2  << 20));  // 16 MB
    bf16* Kb = (bf16*)(ws + ((size_t)18 << 20));  // 16 MB
    bf16* Vb = (bf16*)(ws + ((size_t)34 << 20));  // 16 MB
    bf16* Cb = (bf16*)(ws + ((size_t)50 << 20));  // 16 MB

    prep_weights<<<4096, 256, 0, stream>>>(Wv, Wk, Wq, Wo, wt);
    gemm_kernel<true, false><<<dim3(128, 4), 256, 0, stream>>>(values, wt,              Vb, nullptr);
    gemm_kernel<true, false><<<dim3(128, 4), 256, 0, stream>>>(keys,   wt + 262144,     Kb, nullptr);
    gemm_kernel<true, false><<<dim3(128, 4), 256, 0, stream>>>(query,  wt + 2 * 262144, Qb, nullptr);
    attn_kernel<<<dim3(4, 8, 8), 512, 0, stream>>>(Qb, Kb, Vb, mask, Cb);
    gemm_kernel<false, true><<<dim3(128, 4), 256, 0, stream>>>(Cb, wt + 3 * 262144, out, bo);
}